// Round 7
// baseline (486.001 us; speedup 1.0000x reference)
//
#include <hip/hip_runtime.h>

#define NN 50000
#define NN_PAD 50048                    // 64-aligned, covers last k_mm tile
#define NE 800000
#define DIM 64
#define TL 4
#define ET 3
#define MH 6
#define NBKT 3
#define NB (NN * NBKT)                  // 150000
#define SCAN_BLK ((NB + 1023) / 1024)   // 147

// ---------------- CSR build: 3 type buckets per node, hop packed in entry ----------------

static __global__ void k_hist3(const int* __restrict__ dst, const int* __restrict__ typ,
                               int* __restrict__ counts) {
    int e = blockIdx.x * blockDim.x + threadIdx.x;
    if (e >= NE) return;
    atomicAdd(&counts[dst[e] * NBKT + typ[e]], 1);
}

static __global__ void k_scanA(const int* __restrict__ counts, int* __restrict__ rs,
                               int* __restrict__ bsum) {
    __shared__ int sm[1024];
    int idx = blockIdx.x * 1024 + threadIdx.x;
    int v = (idx < NB) ? counts[idx] : 0;
    sm[threadIdx.x] = v;
    __syncthreads();
    for (int off = 1; off < 1024; off <<= 1) {
        int t = (threadIdx.x >= off) ? sm[threadIdx.x - off] : 0;
        __syncthreads();
        sm[threadIdx.x] += t;
        __syncthreads();
    }
    if (idx < NB) rs[idx] = sm[threadIdx.x] - v;   // exclusive within block
    if (threadIdx.x == 1023) bsum[blockIdx.x] = sm[1023];
}

static __global__ void k_scanB(const int* __restrict__ bsum, int* __restrict__ bexcl,
                               int* __restrict__ rs) {
    __shared__ int sm[512];
    int tid = threadIdx.x;
    int v = (tid < SCAN_BLK) ? bsum[tid] : 0;
    sm[tid] = v;
    __syncthreads();
    for (int off = 1; off < 512; off <<= 1) {
        int t = (tid >= off) ? sm[tid - off] : 0;
        __syncthreads();
        sm[tid] += t;
        __syncthreads();
    }
    if (tid < SCAN_BLK) bexcl[tid] = sm[tid] - v;
    if (tid == 511) rs[NB] = sm[511];              // grand total
}

static __global__ void k_scanC(int* __restrict__ rs, int* __restrict__ cursor,
                               const int* __restrict__ bexcl) {
    int idx = blockIdx.x * 1024 + threadIdx.x;
    if (idx >= NB) return;
    int r = rs[idx] + bexcl[blockIdx.x];
    rs[idx] = r;
    cursor[idx] = r;
}

static __global__ void k_scatter3(const int* __restrict__ src, const int* __restrict__ dst,
                                  const int* __restrict__ typ, const int* __restrict__ hop,
                                  int* __restrict__ cursor, unsigned int* __restrict__ src_s) {
    int e = blockIdx.x * blockDim.x + threadIdx.x;
    if (e >= NE) return;
    int slot = atomicAdd(&cursor[dst[e] * NBKT + typ[e]], 1);
    src_s[slot] = (unsigned int)src[e] | ((unsigned int)hop[e] << 16);
}

// ---------------- Aggregation: one wave per node, single gather feeds type AND hop sums ----
// Gk[t] = segment_sum over hop-k edges of x_t  -> consumed by layer t+k-1's matmul.
// Hop sums reuse the row already loaded for the type sum: zero extra gather traffic.

template <int T>
static __global__ __launch_bounds__(256) void k_agg(
        const int* __restrict__ rs, const unsigned int* __restrict__ src_s,
        const float* __restrict__ xt, const float* __restrict__ nu_edge,
        float* __restrict__ aAll, float* __restrict__ g2,
        float* __restrict__ g3, float* __restrict__ g4) {
    int g = blockIdx.x * blockDim.x + threadIdx.x;
    int node = g >> 6;
    if (node >= NN) return;
    int lane = g & 63;

    int ro = 0;
    if (lane < 4) ro = rs[node * NBKT + lane];
    const int b0 = __builtin_amdgcn_readlane(ro, 0);
    const int b1 = __builtin_amdgcn_readlane(ro, 1);
    const int b2 = __builtin_amdgcn_readlane(ro, 2);
    const int b3 = __builtin_amdgcn_readlane(ro, 3);
    const int nt = b3 - b0, t1 = b1 - b0, t2 = b2 - b0;

    float s0 = 0.f, s1 = 0.f, s2 = 0.f;
    float h2 = 0.f, h3 = 0.f, h4 = 0.f;

    if (nt <= 64) {
        int sv = (lane < nt) ? (int)src_s[b0 + lane] : 0;
#pragma unroll 4
        for (int i = 0; i < nt; ++i) {
            unsigned int sp = (unsigned int)__builtin_amdgcn_readlane(sv, i);  // SGPR
            int srcn = (int)(sp & 0xFFFFu);
            int hop = (int)(sp >> 16);
            float v = xt[(size_t)srcn * DIM + lane];
            s0 = fmaf((i < t1) ? 1.f : 0.f, v, s0);
            s1 = fmaf((i >= t1 && i < t2) ? 1.f : 0.f, v, s1);
            s2 = fmaf((i >= t2) ? 1.f : 0.f, v, s2);
            if (T <= 2) h2 = fmaf((hop == 2) ? 1.f : 0.f, v, h2);
            if (T <= 1) h3 = fmaf((hop == 3) ? 1.f : 0.f, v, h3);
            if (T == 0) h4 = fmaf((hop == 4) ? 1.f : 0.f, v, h4);
        }
    } else {
        for (int i = 0; i < nt; ++i) {
            unsigned int sp = src_s[b0 + i];           // uniform address, broadcast
            int srcn = (int)(sp & 0xFFFFu);
            int hop = (int)(sp >> 16);
            float v = xt[(size_t)srcn * DIM + lane];
            s0 = fmaf((i < t1) ? 1.f : 0.f, v, s0);
            s1 = fmaf((i >= t1 && i < t2) ? 1.f : 0.f, v, s1);
            s2 = fmaf((i >= t2) ? 1.f : 0.f, v, s2);
            if (T <= 2) h2 = fmaf((hop == 2) ? 1.f : 0.f, v, h2);
            if (T <= 1) h3 = fmaf((hop == 3) ? 1.f : 0.f, v, h3);
            if (T == 0) h4 = fmaf((hop == 4) ? 1.f : 0.f, v, h4);
        }
    }

    float nu0 = nu_edge[0 * TL + T], nu1 = nu_edge[1 * TL + T], nu2 = nu_edge[2 * TL + T];
    size_t po = (size_t)node * DIM + lane;
    aAll[(size_t)0 * NN_PAD * DIM + po] = nu0 * s0;
    aAll[(size_t)1 * NN_PAD * DIM + po] = nu1 * s1;
    aAll[(size_t)2 * NN_PAD * DIM + po] = nu2 * s2;
    if (T <= 2) g2[po] = h2;
    if (T <= 1) g3[po] = h3;
    if (T == 0) g4[po] = h4;
}

// ---------------- Matmul: lane = node, W via wave-uniform scalar loads ----------------
// Hop A-row assembled on the fly: nk2*G2[T-1] + nk3*G3[T-2] + nk4*G4[T-3].

__device__ __forceinline__ float4 f4_fma(float s, float4 a, float4 acc) {
    acc.x = fmaf(s, a.x, acc.x);
    acc.y = fmaf(s, a.y, acc.y);
    acc.z = fmaf(s, a.z, acc.z);
    acc.w = fmaf(s, a.w, acc.w);
    return acc;
}

template <int T>
static __global__ __launch_bounds__(256) void k_mm(
        const float* __restrict__ aAll,
        const float* __restrict__ g2, const float* __restrict__ g3,
        const float* __restrict__ g4,
        const float* __restrict__ W_edge, const float* __restrict__ b_edge,
        const float* __restrict__ nu_edge,
        const float* __restrict__ W_t, const float* __restrict__ b_t,
        const float* __restrict__ nu_kt,
        const float* __restrict__ xin, float* __restrict__ xout) {
    const int w = __builtin_amdgcn_readfirstlane(threadIdx.x >> 6);  // uniform wave id
    const int lane = threadIdx.x & 63;
    const int node = blockIdx.x * 64 + lane;     // lane = node within tile
    const int c0 = w * 16;

    const float nu0 = nu_edge[0 * TL + T], nu1 = nu_edge[1 * TL + T],
                nu2 = nu_edge[2 * TL + T];
    const float nk2 = (T >= 1) ? nu_kt[T * MH + 2] : 0.f;
    const float nk3 = (T >= 2) ? nu_kt[T * MH + 3] : 0.f;
    const float nk4 = (T >= 3) ? nu_kt[T * MH + 4] : 0.f;
    const float nsum = nk2 + nk3 + nk4;

    float acc[16];
#pragma unroll
    for (int c = 0; c < 16; ++c) {
        float b = nu0 * b_edge[(0 * TL + T) * DIM + c0 + c]
                + nu1 * b_edge[(1 * TL + T) * DIM + c0 + c]
                + nu2 * b_edge[(2 * TL + T) * DIM + c0 + c];
        if (T >= 1) b = fmaf(nsum, b_t[T * DIM + c0 + c], b);
        acc[c] = b;
    }

    const size_t rowoff = ((size_t)blockIdx.x * 64 + lane) * DIM;
    constexpr int NM = (T >= 1) ? 4 : 3;
#pragma unroll
    for (int m = 0; m < NM; ++m) {
        const float* __restrict__ W = (m == 3) ? (W_t + (size_t)T * DIM * DIM)
                                               : (W_edge + (size_t)(m * TL + T) * DIM * DIM);
        const float4* __restrict__ A4 =
            (const float4*)(aAll + (size_t)m * NN_PAD * DIM + rowoff);
        const float4* __restrict__ G2r = (const float4*)(g2 + rowoff);
        const float4* __restrict__ G3r = (const float4*)(g3 + rowoff);
        const float4* __restrict__ G4r = (const float4*)(g4 + rowoff);
#pragma unroll 4
        for (int dg = 0; dg < 16; ++dg) {
            float4 av;
            if (m < 3) {
                av = A4[dg];
            } else {
                av = make_float4(0.f, 0.f, 0.f, 0.f);
                av = f4_fma(nk2, G2r[dg], av);
                if (T >= 2) av = f4_fma(nk3, G3r[dg], av);
                if (T >= 3) av = f4_fma(nk4, G4r[dg], av);
            }
#pragma unroll
            for (int jd = 0; jd < 4; ++jd) {
                const float* __restrict__ Wr = W + (dg * 4 + jd) * DIM + c0;  // wave-uniform
                float a = (jd == 0) ? av.x : (jd == 1) ? av.y : (jd == 2) ? av.z : av.w;
#pragma unroll
                for (int c = 0; c < 16; ++c)
                    acc[c] = fmaf(a, Wr[c], acc[c]);   // s_load W + v_fmac
            }
        }
    }

    if (node < NN) {
        const float4* __restrict__ X4 = (const float4*)(xin + (size_t)node * DIM + c0);
        float4* __restrict__ O4 = (float4*)(xout + (size_t)node * DIM + c0);
#pragma unroll
        for (int q = 0; q < 4; ++q) {
            float4 xv = X4[q];
            float4 ov;
            ov.x = xv.x + fmaxf(acc[q * 4 + 0], 0.f);
            ov.y = xv.y + fmaxf(acc[q * 4 + 1], 0.f);
            ov.z = xv.z + fmaxf(acc[q * 4 + 2], 0.f);
            ov.w = xv.w + fmaxf(acc[q * 4 + 3], 0.f);
            O4[q] = ov;
        }
    }
}

// ---------------- Host ----------------

extern "C" void kernel_launch(void* const* d_in, const int* in_sizes, int n_in,
                              void* d_out, int out_size, void* d_ws, size_t ws_size,
                              hipStream_t stream) {
    const float* x       = (const float*)d_in[0];
    const float* W_edge  = (const float*)d_in[1];
    const float* b_edge  = (const float*)d_in[2];
    const float* nu_edge = (const float*)d_in[3];
    const float* W_t     = (const float*)d_in[4];
    const float* b_t     = (const float*)d_in[5];
    const float* nu_kt   = (const float*)d_in[6];
    const int* esrc = (const int*)d_in[7];
    const int* edst = (const int*)d_in[8];
    const int* ehop = (const int*)d_in[9];
    const int* etyp = (const int*)d_in[10];
    float* out = (float*)d_out;

    char* ws = (char*)d_ws;
    size_t off = 0;
    auto alloc = [&](size_t bytes) {
        void* p = ws + off;
        off = (off + bytes + 255) & ~(size_t)255;
        return p;
    };
    const size_t PL = (size_t)NN_PAD * DIM * 4;      // one feature plane
    int* counts = (int*)alloc((size_t)NB * 4);
    int* rs     = (int*)alloc(((size_t)NB + 1) * 4);
    int* cursor = (int*)alloc((size_t)NB * 4);
    int* bsum   = (int*)alloc(1024 * 4);
    int* bexcl  = (int*)alloc(1024 * 4);
    unsigned int* src_s = (unsigned int*)alloc((size_t)NE * 4);
    float* hA   = (float*)alloc(PL);                 // ping-pong layer outputs
    float* hB   = (float*)alloc(PL);
    float* aAll = (float*)alloc(3 * PL);             // type planes [3][NN_PAD][64]
    float* G2A  = (float*)alloc(PL);                 // rolling hop-sum planes
    float* G2B  = (float*)alloc(PL);
    float* G3A  = (float*)alloc(PL);
    float* G3B  = (float*)alloc(PL);
    float* G4   = (float*)alloc(PL);
    (void)ws_size; (void)in_sizes; (void)n_in; (void)out_size;

    // CSR build (graph static across layers)
    hipMemsetAsync(counts, 0, (size_t)NB * 4, stream);
    k_hist3<<<(NE + 255) / 256, 256, 0, stream>>>(edst, etyp, counts);
    k_scanA<<<SCAN_BLK, 1024, 0, stream>>>(counts, rs, bsum);
    k_scanB<<<1, 512, 0, stream>>>(bsum, bexcl, rs);
    k_scanC<<<SCAN_BLK, 1024, 0, stream>>>(rs, cursor, bexcl);
    k_scatter3<<<(NE + 255) / 256, 256, 0, stream>>>(esrc, edst, etyp, ehop, cursor, src_s);

    const int ga = (NN * DIM + 255) / 256;   // one wave per node
    const int gm = NN_PAD / 64;              // 782 blocks, 64-node tile each

    // t = 0: hop sums G2[0],G3[0],G4[0] from x
    k_agg<0><<<ga, 256, 0, stream>>>(rs, src_s, x, nu_edge, aAll, G2A, G3A, G4);
    k_mm<0><<<gm, 256, 0, stream>>>(aAll, aAll, aAll, aAll, W_edge, b_edge, nu_edge,
                                    W_t, b_t, nu_kt, x, hA);
    // t = 1: G2[1],G3[1] from hA; matmul hop row = nk2*G2[0]
    k_agg<1><<<ga, 256, 0, stream>>>(rs, src_s, hA, nu_edge, aAll, G2B, G3B, G4);
    k_mm<1><<<gm, 256, 0, stream>>>(aAll, G2A, aAll, aAll, W_edge, b_edge, nu_edge,
                                    W_t, b_t, nu_kt, hA, hB);
    // t = 2: G2[2] from hB; hop row = nk2*G2[1] + nk3*G3[0]
    k_agg<2><<<ga, 256, 0, stream>>>(rs, src_s, hB, nu_edge, aAll, G2A, G3A, G4);
    k_mm<2><<<gm, 256, 0, stream>>>(aAll, G2B, G3A, aAll, W_edge, b_edge, nu_edge,
                                    W_t, b_t, nu_kt, hB, hA);
    // t = 3: no hop sums; hop row = nk2*G2[2] + nk3*G3[1] + nk4*G4[0]
    k_agg<3><<<ga, 256, 0, stream>>>(rs, src_s, hA, nu_edge, aAll, G2B, G3B, G4);
    k_mm<3><<<gm, 256, 0, stream>>>(aAll, G2A, G3B, G4, W_edge, b_edge, nu_edge,
                                    W_t, b_t, nu_kt, hA, out);
}

// Round 8
// 472.889 us; speedup vs baseline: 1.0277x; 1.0277x over previous
//
#include <hip/hip_runtime.h>

#define NN 50000
#define NN_PAD 50048                    // 64-aligned, covers last k_mm tile
#define NE 800000
#define DIM 64
#define TL 4
#define ET 3
#define MH 6
#define NBKT 3
#define NB (NN * NBKT)                  // 150000
#define SCAN_BLK ((NB + 1023) / 1024)   // 147

// ---------------- CSR build: 3 type buckets per node, hop packed in entry ----------------

static __global__ void k_hist3(const int* __restrict__ dst, const int* __restrict__ typ,
                               int* __restrict__ counts) {
    int e = blockIdx.x * blockDim.x + threadIdx.x;
    if (e >= NE) return;
    atomicAdd(&counts[dst[e] * NBKT + typ[e]], 1);
}

static __global__ void k_scanA(const int* __restrict__ counts, int* __restrict__ rs,
                               int* __restrict__ bsum) {
    __shared__ int sm[1024];
    int idx = blockIdx.x * 1024 + threadIdx.x;
    int v = (idx < NB) ? counts[idx] : 0;
    sm[threadIdx.x] = v;
    __syncthreads();
    for (int off = 1; off < 1024; off <<= 1) {
        int t = (threadIdx.x >= off) ? sm[threadIdx.x - off] : 0;
        __syncthreads();
        sm[threadIdx.x] += t;
        __syncthreads();
    }
    if (idx < NB) rs[idx] = sm[threadIdx.x] - v;   // exclusive within block
    if (threadIdx.x == 1023) bsum[blockIdx.x] = sm[1023];
}

static __global__ void k_scanB(const int* __restrict__ bsum, int* __restrict__ bexcl,
                               int* __restrict__ rs) {
    __shared__ int sm[512];
    int tid = threadIdx.x;
    int v = (tid < SCAN_BLK) ? bsum[tid] : 0;
    sm[tid] = v;
    __syncthreads();
    for (int off = 1; off < 512; off <<= 1) {
        int t = (tid >= off) ? sm[tid - off] : 0;
        __syncthreads();
        sm[tid] += t;
        __syncthreads();
    }
    if (tid < SCAN_BLK) bexcl[tid] = sm[tid] - v;
    if (tid == 511) rs[NB] = sm[511];              // grand total
}

static __global__ void k_scanC(int* __restrict__ rs, int* __restrict__ cursor,
                               const int* __restrict__ bexcl) {
    int idx = blockIdx.x * 1024 + threadIdx.x;
    if (idx >= NB) return;
    int r = rs[idx] + bexcl[blockIdx.x];
    rs[idx] = r;
    cursor[idx] = r;
}

static __global__ void k_scatter3(const int* __restrict__ src, const int* __restrict__ dst,
                                  const int* __restrict__ typ, const int* __restrict__ hop,
                                  int* __restrict__ cursor, unsigned int* __restrict__ src_s) {
    int e = blockIdx.x * blockDim.x + threadIdx.x;
    if (e >= NE) return;
    int slot = atomicAdd(&cursor[dst[e] * NBKT + typ[e]], 1);
    src_s[slot] = (unsigned int)src[e] | ((unsigned int)hop[e] << 16);
}

// ---------------- Aggregation: one wave per node; gather feeds type AND hop sums ----------
// Also assembles THIS layer's hop A-row from prior G planes (coalesced) -> aAll[3].

template <int T>
static __global__ __launch_bounds__(256) void k_agg(
        const int* __restrict__ rs, const unsigned int* __restrict__ src_s,
        const float* __restrict__ xt,
        const float* __restrict__ nu_edge, const float* __restrict__ nu_kt,
        const float* __restrict__ gp2, const float* __restrict__ gp3,
        const float* __restrict__ gp4,
        float* __restrict__ aAll, float* __restrict__ g2,
        float* __restrict__ g3, float* __restrict__ g4) {
    int g = blockIdx.x * blockDim.x + threadIdx.x;
    int node = g >> 6;
    if (node >= NN) return;
    int lane = g & 63;
    const size_t po = (size_t)node * DIM + lane;

    // hop A-row for this layer's matmul: coalesced loads, independent of gather loop
    float hp = 0.f;
    if (T >= 1) {
        hp = nu_kt[T * MH + 2] * gp2[po];
        if (T >= 2) hp = fmaf(nu_kt[T * MH + 3], gp3[po], hp);
        if (T >= 3) hp = fmaf(nu_kt[T * MH + 4], gp4[po], hp);
    }

    int ro = 0;
    if (lane < 4) ro = rs[node * NBKT + lane];
    const int b0 = __builtin_amdgcn_readlane(ro, 0);
    const int b1 = __builtin_amdgcn_readlane(ro, 1);
    const int b2 = __builtin_amdgcn_readlane(ro, 2);
    const int b3 = __builtin_amdgcn_readlane(ro, 3);
    const int nt = b3 - b0, t1 = b1 - b0, t2 = b2 - b0;

    float s0 = 0.f, s1 = 0.f, s2 = 0.f;
    float h2 = 0.f, h3 = 0.f, h4 = 0.f;

    if (nt <= 64) {
        int sv = (lane < nt) ? (int)src_s[b0 + lane] : 0;
#pragma unroll 4
        for (int i = 0; i < nt; ++i) {
            unsigned int sp = (unsigned int)__builtin_amdgcn_readlane(sv, i);  // SGPR
            int srcn = (int)(sp & 0xFFFFu);
            int hop = (int)(sp >> 16);
            float v = xt[(size_t)srcn * DIM + lane];
            s0 = fmaf((i < t1) ? 1.f : 0.f, v, s0);
            s1 = fmaf((i >= t1 && i < t2) ? 1.f : 0.f, v, s1);
            s2 = fmaf((i >= t2) ? 1.f : 0.f, v, s2);
            if (T <= 2) h2 = fmaf((hop == 2) ? 1.f : 0.f, v, h2);
            if (T <= 1) h3 = fmaf((hop == 3) ? 1.f : 0.f, v, h3);
            if (T == 0) h4 = fmaf((hop == 4) ? 1.f : 0.f, v, h4);
        }
    } else {
        for (int i = 0; i < nt; ++i) {
            unsigned int sp = src_s[b0 + i];           // uniform address, broadcast
            int srcn = (int)(sp & 0xFFFFu);
            int hop = (int)(sp >> 16);
            float v = xt[(size_t)srcn * DIM + lane];
            s0 = fmaf((i < t1) ? 1.f : 0.f, v, s0);
            s1 = fmaf((i >= t1 && i < t2) ? 1.f : 0.f, v, s1);
            s2 = fmaf((i >= t2) ? 1.f : 0.f, v, s2);
            if (T <= 2) h2 = fmaf((hop == 2) ? 1.f : 0.f, v, h2);
            if (T <= 1) h3 = fmaf((hop == 3) ? 1.f : 0.f, v, h3);
            if (T == 0) h4 = fmaf((hop == 4) ? 1.f : 0.f, v, h4);
        }
    }

    float nu0 = nu_edge[0 * TL + T], nu1 = nu_edge[1 * TL + T], nu2 = nu_edge[2 * TL + T];
    aAll[(size_t)0 * NN_PAD * DIM + po] = nu0 * s0;
    aAll[(size_t)1 * NN_PAD * DIM + po] = nu1 * s1;
    aAll[(size_t)2 * NN_PAD * DIM + po] = nu2 * s2;
    if (T >= 1) aAll[(size_t)3 * NN_PAD * DIM + po] = hp;
    if (T <= 2) g2[po] = h2;
    if (T <= 1) g3[po] = h3;
    if (T == 0) g4[po] = h4;
}

// ---------------- Matmul: lane = node, W via wave-uniform scalar loads (R6 form) --------

template <int T>
static __global__ __launch_bounds__(256) void k_mm(
        const float* __restrict__ aAll,
        const float* __restrict__ W_edge, const float* __restrict__ b_edge,
        const float* __restrict__ nu_edge,
        const float* __restrict__ W_t, const float* __restrict__ b_t,
        const float* __restrict__ nu_kt,
        const float* __restrict__ xin, float* __restrict__ xout) {
    const int w = __builtin_amdgcn_readfirstlane(threadIdx.x >> 6);  // uniform wave id
    const int lane = threadIdx.x & 63;
    const int node = blockIdx.x * 64 + lane;     // lane = node within tile
    const int c0 = w * 16;

    const float nu0 = nu_edge[0 * TL + T], nu1 = nu_edge[1 * TL + T],
                nu2 = nu_edge[2 * TL + T];
    float nsum = 0.f;
    if (T >= 1) {
        nsum = nu_kt[T * MH + 2];
        if (T >= 2) nsum += nu_kt[T * MH + 3];
        if (T >= 3) nsum += nu_kt[T * MH + 4];
    }

    float acc[16];
#pragma unroll
    for (int c = 0; c < 16; ++c) {
        float b = nu0 * b_edge[(0 * TL + T) * DIM + c0 + c]
                + nu1 * b_edge[(1 * TL + T) * DIM + c0 + c]
                + nu2 * b_edge[(2 * TL + T) * DIM + c0 + c];
        if (T >= 1) b = fmaf(nsum, b_t[T * DIM + c0 + c], b);
        acc[c] = b;
    }

    const size_t rowoff = ((size_t)blockIdx.x * 64 + lane) * DIM;
    constexpr int NM = (T >= 1) ? 4 : 3;
#pragma unroll
    for (int m = 0; m < NM; ++m) {
        const float* __restrict__ W = (m == 3) ? (W_t + (size_t)T * DIM * DIM)
                                               : (W_edge + (size_t)(m * TL + T) * DIM * DIM);
        const float4* __restrict__ A4 =
            (const float4*)(aAll + (size_t)m * NN_PAD * DIM + rowoff);
#pragma unroll 4
        for (int dg = 0; dg < 16; ++dg) {
            float4 av = A4[dg];
#pragma unroll
            for (int jd = 0; jd < 4; ++jd) {
                const float* __restrict__ Wr = W + (dg * 4 + jd) * DIM + c0;  // wave-uniform
                float a = (jd == 0) ? av.x : (jd == 1) ? av.y : (jd == 2) ? av.z : av.w;
#pragma unroll
                for (int c = 0; c < 16; ++c)
                    acc[c] = fmaf(a, Wr[c], acc[c]);   // s_load W + v_fmac
            }
        }
    }

    if (node < NN) {
        const float4* __restrict__ X4 = (const float4*)(xin + (size_t)node * DIM + c0);
        float4* __restrict__ O4 = (float4*)(xout + (size_t)node * DIM + c0);
#pragma unroll
        for (int q = 0; q < 4; ++q) {
            float4 xv = X4[q];
            float4 ov;
            ov.x = xv.x + fmaxf(acc[q * 4 + 0], 0.f);
            ov.y = xv.y + fmaxf(acc[q * 4 + 1], 0.f);
            ov.z = xv.z + fmaxf(acc[q * 4 + 2], 0.f);
            ov.w = xv.w + fmaxf(acc[q * 4 + 3], 0.f);
            O4[q] = ov;
        }
    }
}

// ---------------- Host ----------------

extern "C" void kernel_launch(void* const* d_in, const int* in_sizes, int n_in,
                              void* d_out, int out_size, void* d_ws, size_t ws_size,
                              hipStream_t stream) {
    const float* x       = (const float*)d_in[0];
    const float* W_edge  = (const float*)d_in[1];
    const float* b_edge  = (const float*)d_in[2];
    const float* nu_edge = (const float*)d_in[3];
    const float* W_t     = (const float*)d_in[4];
    const float* b_t     = (const float*)d_in[5];
    const float* nu_kt   = (const float*)d_in[6];
    const int* esrc = (const int*)d_in[7];
    const int* edst = (const int*)d_in[8];
    const int* ehop = (const int*)d_in[9];
    const int* etyp = (const int*)d_in[10];
    float* out = (float*)d_out;

    char* ws = (char*)d_ws;
    size_t off = 0;
    auto alloc = [&](size_t bytes) {
        void* p = ws + off;
        off = (off + bytes + 255) & ~(size_t)255;
        return p;
    };
    const size_t PL = (size_t)NN_PAD * DIM * 4;      // one feature plane
    int* counts = (int*)alloc((size_t)NB * 4);
    int* rs     = (int*)alloc(((size_t)NB + 1) * 4);
    int* cursor = (int*)alloc((size_t)NB * 4);
    int* bsum   = (int*)alloc(1024 * 4);
    int* bexcl  = (int*)alloc(1024 * 4);
    unsigned int* src_s = (unsigned int*)alloc((size_t)NE * 4);
    float* hA   = (float*)alloc(PL);                 // ping-pong layer outputs
    float* hB   = (float*)alloc(PL);
    float* aAll = (float*)alloc(4 * PL);             // [type0,type1,type2,hop][NN_PAD][64]
    float* G2A  = (float*)alloc(PL);                 // rolling hop-sum planes
    float* G2B  = (float*)alloc(PL);
    float* G3A  = (float*)alloc(PL);
    float* G3B  = (float*)alloc(PL);
    float* G4   = (float*)alloc(PL);
    (void)ws_size; (void)in_sizes; (void)n_in; (void)out_size;

    // CSR build (graph static across layers)
    hipMemsetAsync(counts, 0, (size_t)NB * 4, stream);
    k_hist3<<<(NE + 255) / 256, 256, 0, stream>>>(edst, etyp, counts);
    k_scanA<<<SCAN_BLK, 1024, 0, stream>>>(counts, rs, bsum);
    k_scanB<<<1, 512, 0, stream>>>(bsum, bexcl, rs);
    k_scanC<<<SCAN_BLK, 1024, 0, stream>>>(rs, cursor, bexcl);
    k_scatter3<<<(NE + 255) / 256, 256, 0, stream>>>(esrc, edst, etyp, ehop, cursor, src_s);

    const int ga = (NN * DIM + 255) / 256;   // one wave per node
    const int gm = NN_PAD / 64;              // 782 blocks, 64-node tile each

    // t = 0: write G2[0],G3[0],G4[0]; no hop row
    k_agg<0><<<ga, 256, 0, stream>>>(rs, src_s, x, nu_edge, nu_kt,
                                     G4, G4, G4, aAll, G2A, G3A, G4);
    k_mm<0><<<gm, 256, 0, stream>>>(aAll, W_edge, b_edge, nu_edge, W_t, b_t, nu_kt, x, hA);
    // t = 1: write G2[1],G3[1]; hop row = nk2*G2[0]
    k_agg<1><<<ga, 256, 0, stream>>>(rs, src_s, hA, nu_edge, nu_kt,
                                     G2A, G4, G4, aAll, G2B, G3B, G4);
    k_mm<1><<<gm, 256, 0, stream>>>(aAll, W_edge, b_edge, nu_edge, W_t, b_t, nu_kt, hA, hB);
    // t = 2: write G2[2] (->G2A, its layer-0 content consumed at t=1);
    //        hop row = nk2*G2[1] + nk3*G3[0]
    k_agg<2><<<ga, 256, 0, stream>>>(rs, src_s, hB, nu_edge, nu_kt,
                                     G2B, G3A, G4, aAll, G2A, G3B, G4);
    k_mm<2><<<gm, 256, 0, stream>>>(aAll, W_edge, b_edge, nu_edge, W_t, b_t, nu_kt, hB, hA);
    // t = 3: no G writes; hop row = nk2*G2[2] + nk3*G3[1] + nk4*G4[0]
    k_agg<3><<<ga, 256, 0, stream>>>(rs, src_s, hA, nu_edge, nu_kt,
                                     G2A, G3B, G4, aAll, G2B, G3B, G4);
    k_mm<3><<<gm, 256, 0, stream>>>(aAll, W_edge, b_edge, nu_edge, W_t, b_t, nu_kt, hA, out);
}